// Round 10
// baseline (1027.430 us; speedup 1.0000x reference)
//
#include <hip/hip_runtime.h>
#include <math.h>

// Problem constants (fixed by reference)
#define S_LEN    1024
#define NHEAD    16
#define DHEAD    128
#define HIDDEN   2048
#define BATCH    2
#define BH       32            // BATCH*NHEAD
#define CACHE_B  204           // heavy+recent budget
#define RECENT_B 102
#define QK_SCALE 0.08838834764831845f   // 1/sqrt(128)

typedef float v2f __attribute__((ext_vector_type(2)));
typedef float f32x4 __attribute__((ext_vector_type(4)));
typedef short short8v __attribute__((ext_vector_type(8)));

// ---------------------------------------------------------------------------
// bf16 hi/lo split helpers (RNE). a = hi + lo captures ~16-17 mantissa bits;
// a*b ~= ah*bh + al*bh + ah*bl (3 MFMAs) -> ~1e-5 abs error on these scales.
// ---------------------------------------------------------------------------
__device__ __forceinline__ unsigned short f2bf(float f) {
  unsigned u = __float_as_uint(f);
  u += 0x7fffu + ((u >> 16) & 1u);
  return (unsigned short)(u >> 16);
}
__device__ __forceinline__ float bf2f(unsigned short h) {
  return __uint_as_float(((unsigned)h) << 16);
}

// async global->LDS, 16B per lane. LDS dest must be wave-uniform base +
// lane*16 (HW ignores per-lane LDS scatter); global source IS per-lane.
__device__ __forceinline__ void gl16(const void* g, void* l) {
  __builtin_amdgcn_global_load_lds(
      (const __attribute__((address_space(1))) unsigned int*)g,
      (__attribute__((address_space(3))) unsigned int*)l, 16, 0, 0);
}

// MFMA via inline asm: avoids builtin signature (short8 vs bf16x8) ambiguity.
// gfx950 unified VGPR/AGPR file -> C/D in plain VGPRs is valid.
__device__ __forceinline__ void mfma_b(f32x4& d, short8v a, short8v b) {
  asm("v_mfma_f32_16x16x32_bf16 %0, %1, %2, %0" : "+v"(d) : "v"(a), "v"(b));
}

// ---------------------------------------------------------------------------
// split_a: X[f32] -> hi,lo bf16 (same layout). 4 elems/thread.
// ---------------------------------------------------------------------------
__global__ __launch_bounds__(256) void split_a(
    const float* __restrict__ X, unsigned short* __restrict__ hi,
    unsigned short* __restrict__ lo) {
  const size_t i = ((size_t)blockIdx.x * 256 + threadIdx.x) * 4;
  const float4 v = *(const float4*)&X[i];
  const float f[4] = {v.x, v.y, v.z, v.w};
  unsigned short h[4], l[4];
#pragma unroll
  for (int j = 0; j < 4; ++j) {
    h[j] = f2bf(f[j]);
    l[j] = f2bf(f[j] - bf2f(h[j]));
  }
  *(ushort4*)&hi[i] = make_ushort4(h[0], h[1], h[2], h[3]);
  *(ushort4*)&lo[i] = make_ushort4(l[0], l[1], l[2], l[3]);
}

// ---------------------------------------------------------------------------
// split_T: W[k][n] f32 -> hiT,loT[n][k] bf16 (transpose+split), 64x64 tiles
// via padded LDS. z selects among up to 3 weights; out block stride 8M shorts.
// ---------------------------------------------------------------------------
__global__ __launch_bounds__(256) void split_T(
    const float* __restrict__ W0, const float* __restrict__ W1,
    const float* __restrict__ W2, unsigned short* __restrict__ outB) {
  __shared__ float Ts[64][65];
  const float* W = (blockIdx.z == 0) ? W0 : ((blockIdx.z == 1) ? W1 : W2);
  unsigned short* hiT = outB + (size_t)blockIdx.z * 8388608u;
  unsigned short* loT = hiT + 4194304u;
  const int k0 = blockIdx.y * 64, n0 = blockIdx.x * 64;
  const int r = threadIdx.x >> 4, c4 = (threadIdx.x & 15) * 4;
#pragma unroll
  for (int it = 0; it < 4; ++it) {
    const float4 v =
        *(const float4*)&W[(size_t)(k0 + it * 16 + r) * HIDDEN + n0 + c4];
    Ts[it * 16 + r][c4 + 0] = v.x;
    Ts[it * 16 + r][c4 + 1] = v.y;
    Ts[it * 16 + r][c4 + 2] = v.z;
    Ts[it * 16 + r][c4 + 3] = v.w;
  }
  __syncthreads();
#pragma unroll
  for (int it = 0; it < 4; ++it) {
    const int n = it * 16 + r;
    unsigned short h[4], l[4];
#pragma unroll
    for (int j = 0; j < 4; ++j) {
      const float f = Ts[c4 + j][n];
      h[j] = f2bf(f);
      l[j] = f2bf(f - bf2f(h[j]));
    }
    const size_t o = (size_t)(n0 + n) * HIDDEN + k0 + c4;
    *(ushort4*)&hiT[o] = make_ushort4(h[0], h[1], h[2], h[3]);
    *(ushort4*)&loT[o] = make_ushort4(l[0], l[1], l[2], l[3]);
  }
}

// ---------------------------------------------------------------------------
// bf16x3 MFMA GEMM, m97 structure: 128x128 tile, BK=32, 256 threads = 4
// waves in 2x2, each wave a 64x64 quadrant as 4x4 fragments of
// v_mfma_f32_16x16x32_bf16. A: [M][K] hi/lo; B: [N][K] (pre-transposed
// weight splits). MODE 0: C scatters to [B,H,S,D] per blockIdx.z.
// MODE 1: row-major C.
// ---------------------------------------------------------------------------
template <int MODE>
__global__ __launch_bounds__(256) void gemm_mfma(
    const unsigned short* __restrict__ Ahi,
    const unsigned short* __restrict__ Alo,
    const unsigned short* __restrict__ WT, float* __restrict__ C0) {
  __shared__ unsigned short AhS[128][32];
  __shared__ unsigned short AlS[128][32];
  __shared__ unsigned short BhS[128][32];
  __shared__ unsigned short BlS[128][32];
  const int tid = threadIdx.x;
  const int lane = tid & 63;
  const int wv = tid >> 6;
  const int wr = wv >> 1, wc = wv & 1;
  const int m0 = blockIdx.y * 128, n0 = blockIdx.x * 128;
  const unsigned short* BhiT =
      WT + (MODE == 0 ? (size_t)blockIdx.z * 8388608u : (size_t)0);
  const unsigned short* BloT = BhiT + 4194304u;

  f32x4 acc[4][4];
#pragma unroll
  for (int i = 0; i < 4; ++i)
#pragma unroll
    for (int j = 0; j < 4; ++j) acc[i][j] = (f32x4)(0.0f);

  const int r_st = tid >> 2;        // staging row base (0..63); +64 on l=1
  const int kc_st = (tid & 3) * 8;  // staging k element offset

  for (int k0 = 0; k0 < HIDDEN; k0 += 32) {
#pragma unroll
    for (int l = 0; l < 2; ++l) {
      const int r = r_st + l * 64;
      const size_t ga = (size_t)(m0 + r) * HIDDEN + (k0 + kc_st);
      const size_t gb = (size_t)(n0 + r) * HIDDEN + (k0 + kc_st);
      gl16(Ahi + ga, &AhS[r][kc_st]);
      gl16(Alo + ga, &AlS[r][kc_st]);
      gl16(BhiT + gb, &BhS[r][kc_st]);
      gl16(BloT + gb, &BlS[r][kc_st]);
    }
    __syncthreads();  // compiler drains vmcnt before barrier
    const int mrow = lane & 15;
    const int kb = (lane >> 4) * 8;
    short8v ah[4], al[4], bh[4], bl[4];
#pragma unroll
    for (int i = 0; i < 4; ++i) {
      ah[i] = *(const short8v*)&AhS[wr * 64 + i * 16 + mrow][kb];
      al[i] = *(const short8v*)&AlS[wr * 64 + i * 16 + mrow][kb];
      bh[i] = *(const short8v*)&BhS[wc * 64 + i * 16 + mrow][kb];
      bl[i] = *(const short8v*)&BlS[wc * 64 + i * 16 + mrow][kb];
    }
#pragma unroll
    for (int i = 0; i < 4; ++i)
#pragma unroll
      for (int j = 0; j < 4; ++j) {
        mfma_b(acc[i][j], ah[i], bh[j]);
        mfma_b(acc[i][j], al[i], bh[j]);
        mfma_b(acc[i][j], ah[i], bl[j]);
      }
    __syncthreads();
  }

  // C/D layout (m89/m91-verified): col = lane&15, row = (lane>>4)*4 + reg
  float* C = C0;
  if (MODE == 0) C += (size_t)blockIdx.z * ((size_t)BH * S_LEN * DHEAD);
#pragma unroll
  for (int i = 0; i < 4; ++i) {
    const int mbase = m0 + wr * 64 + i * 16 + ((lane >> 4) * 4);
#pragma unroll
    for (int j = 0; j < 4; ++j) {
      const int n = n0 + wc * 64 + j * 16 + (lane & 15);
#pragma unroll
      for (int rg = 0; rg < 4; ++rg) {
        const int m = mbase + rg;
        const float val = acc[i][j][rg];
        if (MODE == 0) {
          const int b = m >> 10, s = m & (S_LEN - 1);
          const int h = n >> 7, d = n & (DHEAD - 1);
          C[(((size_t)(b * NHEAD + h) * S_LEN + s) * DHEAD) + d] = val;
        } else {
          C[(size_t)m * HIDDEN + n] = val;
        }
      }
    }
  }
}

// ---------------------------------------------------------------------------
// RoPE in place on Q,K ([BH,S,D] layout).
// ---------------------------------------------------------------------------
__global__ __launch_bounds__(256) void rope_qk(float* __restrict__ Q,
                                               float* __restrict__ K) {
  int g = blockIdx.x * 4 + (threadIdx.x >> 6);  // row id over BH*S
  int lane = threadIdx.x & 63;
  int s = g & (S_LEN - 1);
  double invf = exp(-((double)(2 * lane) / 128.0) * log(10000.0));
  float angle = (float)s * (float)invf;
  float c = (float)cos((double)angle);
  float sn = (float)sin((double)angle);
  size_t base = (size_t)g * DHEAD;
  float q0 = Q[base + lane], q1 = Q[base + lane + 64];
  Q[base + lane] = q0 * c - q1 * sn;
  Q[base + lane + 64] = q1 * c + q0 * sn;
  float k0 = K[base + lane], k1 = K[base + lane + 64];
  K[base + lane] = k0 * c - k1 * sn;
  K[base + lane + 64] = k1 * c + k0 * sn;
}

// ---------------------------------------------------------------------------
// Per (b,h): mean |k| over first 204 roped tokens, stable argsort rank,
// keep top-6 dims; pack Qp[bh][s][0..5] (stride 8) and TRANSPOSED
// KpT[bh][j][s] (j=0..5, stride S_LEN) for attn_av's branchless phase 1.
// ---------------------------------------------------------------------------
__global__ __launch_bounds__(128) void keep_pack(
    const float* __restrict__ Q, const float* __restrict__ K,
    float* __restrict__ Qp, float* __restrict__ KpT) {
  int bh = blockIdx.x;
  int d = threadIdx.x;
  __shared__ float ma[128];
  __shared__ int kf[128];
  __shared__ int kidx[8];
  const float* Kb = K + (size_t)bh * S_LEN * DHEAD;
  const float* Qb = Q + (size_t)bh * S_LEN * DHEAD;
  float sum = 0.0f;
  for (int s = 0; s < CACHE_B; ++s) sum += fabsf(Kb[(size_t)s * DHEAD + d]);
  ma[d] = sum / 204.0f;
  __syncthreads();
  float v = ma[d];
  int rank = 0;
  for (int e = 0; e < 128; ++e) {
    float u = ma[e];
    rank += (u < v) || (u == v && e < d);  // stable-argsort rank
  }
  int keep = (rank >= 128 - 6);
  kf[d] = keep;
  __syncthreads();
  if (keep) {
    int pos = 0;
    for (int e = 0; e < d; ++e) pos += kf[e];
    kidx[pos] = d;
  }
  __syncthreads();
  int i0 = kidx[0], i1 = kidx[1], i2 = kidx[2];
  int i3 = kidx[3], i4 = kidx[4], i5 = kidx[5];
  float* Kt = KpT + (size_t)bh * 6 * S_LEN;
  for (int s = threadIdx.x; s < S_LEN; s += 128) {
    size_t src = (size_t)s * DHEAD;
    size_t dst = ((size_t)bh * S_LEN + s) * 8;
    Qp[dst + 0] = Qb[src + i0]; Qp[dst + 1] = Qb[src + i1];
    Qp[dst + 2] = Qb[src + i2]; Qp[dst + 3] = Qb[src + i3];
    Qp[dst + 4] = Qb[src + i4]; Qp[dst + 5] = Qb[src + i5];
    Kt[0 * S_LEN + s] = Kb[src + i0];
    Kt[1 * S_LEN + s] = Kb[src + i1];
    Kt[2 * S_LEN + s] = Kb[src + i2];
    Kt[3 * S_LEN + s] = Kb[src + i3];
    Kt[4 * S_LEN + s] = Kb[src + i4];
    Kt[5 * S_LEN + s] = Kb[src + i5];
  }
}

// ---------------------------------------------------------------------------
// Batched A_full[bh][t][s] = QK_SCALE * Q[t]·K[s], lower-triangular tiles
// only. fp32 (exactness matters for the eviction argmin path).
// ---------------------------------------------------------------------------
__global__ __launch_bounds__(256) void qkt_scores(
    const float* __restrict__ Q, const float* __restrict__ K,
    float* __restrict__ Af) {
  if (blockIdx.x > blockIdx.y) return;  // strictly-upper tiles never read
  __shared__ float Qs[16][132];
  __shared__ float Ks[16][132];
  const int bh = blockIdx.z;
  const int tid = threadIdx.x;
  const int tx = tid & 15, ty = tid >> 4;
  const int m0 = blockIdx.y * 128, n0 = blockIdx.x * 128;
  const float* Qb = Q + (size_t)bh * S_LEN * DHEAD;
  const float* Kb = K + (size_t)bh * S_LEN * DHEAD;
  v2f acc[8][4];
#pragma unroll
  for (int i = 0; i < 8; ++i)
#pragma unroll
    for (int p = 0; p < 4; ++p) acc[i][p] = (v2f)(0.0f);

  for (int k0 = 0; k0 < DHEAD; k0 += 16) {
#pragma unroll
    for (int l = 0; l < 2; ++l) {
      int f = tid + l * 256;
      int r = f >> 2, c = (f & 3) * 4;
      const float4 q = *(const float4*)&Qb[(size_t)(m0 + r) * DHEAD + k0 + c];
      Qs[c + 0][r] = q.x; Qs[c + 1][r] = q.y;
      Qs[c + 2][r] = q.z; Qs[c + 3][r] = q.w;
      const float4 kv = *(const float4*)&Kb[(size_t)(n0 + r) * DHEAD + k0 + c];
      Ks[c + 0][r] = kv.x; Ks[c + 1][r] = kv.y;
      Ks[c + 2][r] = kv.z; Ks[c + 3][r] = kv.w;
    }
    __syncthreads();
#pragma unroll
    for (int kk = 0; kk < 16; ++kk) {
      float av[8];
      v2f bv[4];
      *(float4*)&av[0] = *(float4*)&Qs[kk][ty * 4];
      *(float4*)&av[4] = *(float4*)&Qs[kk][64 + ty * 4];
      const float4 b0 = *(const float4*)&Ks[kk][tx * 4];
      const float4 b1 = *(const float4*)&Ks[kk][64 + tx * 4];
      bv[0] = (v2f){b0.x, b0.y};
      bv[1] = (v2f){b0.z, b0.w};
      bv[2] = (v2f){b1.x, b1.y};
      bv[3] = (v2f){b1.z, b1.w};
#pragma unroll
      for (int i = 0; i < 8; ++i) {
        const v2f a2 = (v2f){av[i], av[i]};
#pragma unroll
        for (int p = 0; p < 4; ++p) acc[i][p] = a2 * bv[p] + acc[i][p];
      }
    }
    __syncthreads();
  }
  float* Cb = Af + (size_t)bh * S_LEN * S_LEN;
#pragma unroll
  for (int gi = 0; gi < 2; ++gi)
#pragma unroll
    for (int i = 0; i < 4; ++i) {
      const int t = m0 + gi * 64 + ty * 4 + i;
      const int ia = gi * 4 + i;
#pragma unroll
      for (int gj = 0; gj < 2; ++gj) {
        const int s = n0 + gj * 64 + tx * 4;
        float4 o;
        o.x = acc[ia][gj * 2 + 0].x * QK_SCALE;
        o.y = acc[ia][gj * 2 + 0].y * QK_SCALE;
        o.z = acc[ia][gj * 2 + 1].x * QK_SCALE;
        o.w = acc[ia][gj * 2 + 1].y * QK_SCALE;
        *(float4*)&Cb[(size_t)t * S_LEN + s] = o;
      }
    }
}

// ---------------------------------------------------------------------------
// Sequential H2O eviction scan v11 — 8 DMA producers + 1 fast consumer.
// Round-9 post-mortem: v10 (speculative top-8) FAILED correctness and the
// flaw resisted inspection -> replaced by a composition of ONLY verified
// pieces: v4's swizzled gl16 staging (passed r2), v8's slot-tournament
// argmin chain (~275 cy/step, passed r6-r8), v3's producer/consumer +
// per-chunk __syncthreads orchestration (ran r1). v3 was slow because its
// consumer chain was ~1880 cy/step; v8's is ~275.
// Structure: producer wave p stages row 204+8*blk+p via gl16 (source
// pre-swizzled w^((w>>3)&7) on 16B units; LDS stays linear) into
// buf[2][8][1024] (exactly 64 KiB, launch-verified size). One __syncthreads
// per 8-step block: producers issue block b+1's loads at iteration start;
// the barrier's implicit vmcnt drain runs in PRODUCER waves concurrently
// with the consumer's ~2400 cy of compute -> latency hidden without any
// compiler pipelining. Consumer = v8's exact step math from LDS; evictions
// written DIRECTLY to global evt (consumer has no global loads -> no vmcnt
// stalls; init+evict stores same-wave ordered, v6/v8-proven).
// ---------------------------------------------------------------------------
template <int CTRL, int RMASK>
__device__ __forceinline__ float dpp_fmin(float x) {
  const int xi = __builtin_bit_cast(int, x);
  const int y = __builtin_amdgcn_update_dpp(xi, xi, CTRL, RMASK, 0xF, false);
  return fminf(x, __builtin_bit_cast(float, y));
}
__device__ __forceinline__ float wave_min_f32(float x) {
  x = dpp_fmin<0x111, 0xF>(x);  // row_shr:1
  x = dpp_fmin<0x112, 0xF>(x);  // row_shr:2
  x = dpp_fmin<0x114, 0xF>(x);  // row_shr:4
  x = dpp_fmin<0x118, 0xF>(x);  // row_shr:8
  x = dpp_fmin<0x142, 0xA>(x);  // row_bcast:15
  x = dpp_fmin<0x143, 0xC>(x);  // row_bcast:31
  return __builtin_bit_cast(
      float, __builtin_amdgcn_readlane(__builtin_bit_cast(int, x), 63));
}

__global__ __launch_bounds__(576, 1) void scan_evict(
    const float* __restrict__ Af, int* __restrict__ evt) {
  __shared__ float buf[2][8][S_LEN];  // 64 KiB exactly
  const int bh = blockIdx.x;
  const int tid = threadIdx.x;
  const int lane = tid & 63;
  const int wv = tid >> 6;  // 0..7 = producers (row p of block), 8 = consumer
  const float* Ab = Af + (size_t)bh * S_LEN * S_LEN;
  int* evtb = evt + bh * S_LEN;

  if (wv < 8) {
    // prologue: stage block 0 (rows 204..211) into buf[0]
    const float* rb = Ab + (size_t)(204 + wv) * S_LEN;
#pragma unroll
    for (int c = 0; c < 4; ++c) {
      const int w = c * 64 + lane;
      const int g = w ^ ((w >> 3) & 7);  // involutive 16B-chunk swizzle
      gl16(rb + g * 4, &buf[0][wv][c * 256 + lane * 4]);
    }
  } else {
    // evt init: INT_MAX everywhere (same-wave ordering vs later evict writes)
    const int4 big = make_int4(0x7fffffff, 0x7fffffff, 0x7fffffff, 0x7fffffff);
    int4* e4 = (int4*)evtb;
#pragma unroll
    for (int j = 0; j < 4; ++j) e4[j * 64 + lane] = big;
  }
  __syncthreads();  // drains producers' gl16 -> buf[0] published

  unsigned evmask = 0;
  unsigned elig = (lane < 6) ? 0xFFFFu : (lane == 6 ? 0x7Fu : 0u);  // s <= 102

  for (int blk = 0; blk < 103; ++blk) {
    if (wv < 8) {
      if (blk + 1 < 103) {  // stage next block while consumer chews this one
        int row = 204 + (blk + 1) * 8 + wv;
        row = row > 1022 ? 1022 : row;  // tail clamp (never consumed)
        const float* rb = Ab + (size_t)row * S_LEN;
        float* dst = &buf[(blk + 1) & 1][wv][0];
#pragma unroll
        for (int c = 0; c < 4; ++c) {
          const int w = c * 64 + lane;
          const int g = w ^ ((w >> 3) & 7);
          gl16(rb + g * 4, dst + c * 256 + lane * 4);
        }
      }
    } else {
      const float* bc = &buf[blk & 1][0][0];
      const int t0 = 205 + blk * 8;
#pragma unroll
      for (int u = 0; u < 8; ++u) {
        const int t = t0 + u;
        if (t > 1023) break;  // wave-uniform
        // row u from LDS (swizzled read matches pre-swizzled source)
        f32x4 cur[4];
#pragma unroll
        for (int p = 0; p < 4; ++p) {
          const int pc = lane * 4 + p;
          const int ph = pc ^ ((pc >> 3) & 7);
          cur[p] = *(const f32x4*)&bc[(size_t)u * S_LEN + ph * 4];
        }
        // newly eligible position s = t-103 (idempotent at t=205)
        const int snew = t - 103;
        elig |= ((snew >> 4) == lane) ? (1u << (snew & 15)) : 0u;
        const unsigned ue = elig & ~evmask;
        float fv[16];
#pragma unroll
        for (int b = 0; b < 16; ++b)
          fv[b] = ((ue >> b) & 1u) ? cur[b >> 2][b & 3] : INFINITY;
        // (min, first-slot) tournament; <= prefers left = lower slot
        float m8[8]; int s8[8];
#pragma unroll
        for (int i = 0; i < 8; ++i) {
          m8[i] = fminf(fv[2 * i], fv[2 * i + 1]);
          s8[i] = (fv[2 * i] <= fv[2 * i + 1]) ? (2 * i) : (2 * i + 1);
        }
        float m4[4]; int s4[4];
#pragma unroll
        for (int i = 0; i < 4; ++i) {
          m4[i] = fminf(m8[2 * i], m8[2 * i + 1]);
          s4[i] = (m8[2 * i] <= m8[2 * i + 1]) ? s8[2 * i] : s8[2 * i + 1];
        }
        float m2[2]; int s2[2];
        m2[0] = fminf(m4[0], m4[1]);
        s2[0] = (m4[0] <= m4[1]) ? s4[0] : s4[1];
        m2[1] = fminf(m4[2], m4[3]);
        s2[1] = (m4[2] <= m4[3]) ? s4[2] : s4[3];
        const float vmin = fminf(m2[0], m2[1]);
        const int bloc = (m2[0] <= m2[1]) ? s2[0] : s2[1];
        const float best = wave_min_f32(vmin);  // wave-uniform global min
        const unsigned long long msk = __ballot(vmin == best);
        const int winner = __ffsll(msk) - 1;  // lowest lane = lowest s
        if (lane == winner) {
          evmask |= 1u << bloc;
          evtb[lane * 16 + bloc] = t;  // global store; never waited on
        }
      }
    }
    __syncthreads();  // producers' loads drained; next buffer published
  }
}

// ---------------------------------------------------------------------------
// Final attention v2 — verified round 7 (dropped out of top-5).
// Phase 1 branchless (KpT + cndmask); phase 2 s-partitioned (1x V traffic),
// cross-wave reduce overlaid on P.
// ---------------------------------------------------------------------------
__global__ __launch_bounds__(256) void attn_av(
    const float* __restrict__ Af, const float* __restrict__ Qp,
    const float* __restrict__ KpT, const int* __restrict__ evt,
    const float* __restrict__ V, float* __restrict__ AO) {
  const int t0 = blockIdx.x * 8;
  const int bh = blockIdx.y;
  __shared__ float P[8][S_LEN];  // 32 KB; first 16 KB reused as reduce buf
  __shared__ float rinv[8];
  const int tid = threadIdx.x;
  const int lane = tid & 63, wave = tid >> 6;
  const float* Ab = Af + (size_t)bh * S_LEN * S_LEN;
  const int* eb = evt + bh * S_LEN;
  const float* Kt = KpT + (size_t)bh * 6 * S_LEN;

  // ---- phase 1: merged scores + softmax -> P, rinv ----
  for (int rr = 0; rr < 2; ++rr) {
    const int r = wave * 2 + rr;
    const int t = t0 + r;
    float qp[6];
#pragma unroll
    for (int j = 0; j < 6; ++j) qp[j] = Qp[((size_t)bh * S_LEN + t) * 8 + j];
    float vals[16];
    float m = -INFINITY;
#pragma unroll
    for (int i = 0; i < 16; ++i) {
      const int s = lane + i * 64;
      const float full = Ab[(size_t)t * S_LEN + s];
      float low = qp[0] * Kt[s];
      low += qp[1] * Kt[S_LEN + s];
      low += qp[2] * Kt[2 * S_LEN + s];
      low += qp[3] * Kt[3 * S_LEN + s];
      low += qp[4] * Kt[4 * S_LEN + s];
      low += qp[5] * Kt[5 * S_LEN + s];
      const int ev = eb[s];
      const float sc = (ev <= t) ? (QK_SCALE * low) : full;
      vals[i] = sc;
      m = fmaxf(m, (s <= t) ? sc : -INFINITY);
    }
    for (int off = 32; off; off >>= 1) m = fmaxf(m, __shfl_xor(m, off, 64));
    float sum = 0.0f;
#pragma unroll
    for (int i = 0; i < 16; ++i) {
      const int s = lane + i * 64;
      const float e = expf(vals[i] - m);
      const float p = (s <= t) ? e : 0.0f;  // select after exp: NaN-safe
      sum += p;
      P[r][s] = p;
    }
    for (int off = 32; off; off >>= 1) sum += __shfl_xor(sum, off, 64);
    if (lane == 0) rinv[r] = 1.0f / sum;
  }
  __syncthreads();

  // ---- phase 2: out = P·V, s-partitioned across waves (1x V traffic) ----
  const int NC = (t0 + 8) >> 2;  // number of 4-row s-chunks
  const float* Vb = V + (size_t)bh * S_LEN * DHEAD;
  const int d2 = lane * 2;
  float accx[8], accy[8];
#pragma unroll
  for (int r = 0; r < 8; ++r) { accx[r] = 0.0f; accy[r] = 0.0f; }
  for (int c = wave; c < NC; c += 4) {
    const int s0 = c * 4;
    float4 p4[8];
#pragma unroll
    for (int r = 0; r < 8; ++r) p4[r] = *(const float4*)&P[r][s0];
    const float2 v0 = *(const float2*)&Vb[(size_t)(s0 + 0) * DHEAD + d2];
    const float2 v1 = *(const float2*)&Vb[(size_t)(s0 + 1) * DHEAD + d2];
    const float2 v2 = *(const float2*)&Vb[(size_t)(s0 + 2) * DHEAD + d2];
    const float2 v3 = *(const float2*)&Vb[(size_t)(s0 + 3) * DHEAD + d2];
#pragma unroll
    for (int r = 0; r < 8; ++r) {
      accx[r] += p4[r].x * v0.x + p4[r].y * v1.x + p4[r].z * v2.x +
                 p4[r].w * v3.x;
      accy[r] += p4[r].x * v0.y + p4[r].y * v1.y + p4[r].z * v2.y +
                 p4[r].w * v3.y;
    }
  }
  __syncthreads();  // all waves done reading P -> safe to overlay
  float* red = &P[0][0];  // red[w][r][128]: 4*8*128 floats = 16 KB
#pragma unroll
  for (int r = 0; r < 8; ++r) {
    float2 pr; pr.x = accx[r]; pr.y = accy[r];
    *(float2*)&red[((wave * 8 + r) << 7) + d2] = pr;
  }
  __syncthreads();
  // final: 1024 outputs; tid -> r = tid>>5, d4 = (tid&31)*4
  const int r = tid >> 5;
  const int d4 = (tid & 31) * 4;
  const int t = t0 + r;
  float4 o = make_float4(0.f, 0.f, 0.f, 0.f);
#pragma unroll
  for (int w = 0; w < 4; ++w) {
    const float4 part = *(const float4*)&red[((w * 8 + r) << 7) + d4];
    o.x += part.x; o.y += part.y; o.z += part.z; o.w += part.w;
  }
  const float ri = rinv[r];
  o.x *= ri; o.y *= ri; o.z *= ri; o.w *= ri;
  const int b = bh >> 4, h = bh & 15;
  *(float4*)&AO[((size_t)(b * S_LEN + t)) * HIDDEN + h * DHEAD + d4] = o;
}

// ---------------------------------------------------------------------------
// Workspace plan: Q,K,V (48MB) | Af (128MB) | Qp | KpT (in Kp's old slot) |
// evt | AO. bf16 split buffers live INSIDE Af (dead until qkt_scores).
// ---------------------------------------------------------------------------
extern "C" void kernel_launch(void* const* d_in, const int* in_sizes, int n_in,
                              void* d_out, int out_size, void* d_ws,
                              size_t ws_size, hipStream_t stream) {
  const float* hs = (const float*)d_in[0];
  const float* wq = (const float*)d_in[1];
  const float* wk = (const float*)d_in[2];
  const float* wv = (const float*)d_in[3];
  const float* wo = (const float*)d_in[4];
  float* out = (float*)d_out;

  const size_t SZ_QKV = (size_t)BH * S_LEN * DHEAD;
  float* Q = (float*)d_ws;
  float* K = Q + SZ_QKV;
  float* V = K + SZ_QKV;
  float* Af = V + SZ_QKV;
  float* Qp = Af + (size_t)BH * S_LEN * S_LEN;
  float* KpT = Qp + (size_t)BH * S_LEN * 8;  // 6*S_LEN*BH floats < old Kp slot
  int* evt = (int*)(KpT + (size_t)BH * S_LEN * 8);
  float* AO = (float*)(evt + BH * S_LEN);

  // split-buffer aliases inside Af (ushort units; block = 2048*2048 = 4194304)
  unsigned short* U = (unsigned short*)Af;
  unsigned short* wT = U;                        // 3 x (hi+lo) = 48 MiB
  unsigned short* hs_hi = U + 25165824u;         // 3*8388608
  unsigned short* hs_lo = hs_hi + 4194304u;
  unsigned short* ao_hi = U;                     // end-phase reuse
  unsigned short* ao_lo = U + 4194304u;
  unsigned short* woT = U + 8388608u;            // hi at +8M, lo at +12M

  split_T<<<dim3(32, 32, 3), 256, 0, stream>>>(wq, wk, wv, wT);
  split_a<<<dim3(4096), 256, 0, stream>>>(hs, hs_hi, hs_lo);
  gemm_mfma<0><<<dim3(16, 16, 3), 256, 0, stream>>>(hs_hi, hs_lo, wT, Q);
  rope_qk<<<dim3(BH * S_LEN / 4), 256, 0, stream>>>(Q, K);
  keep_pack<<<dim3(BH), 128, 0, stream>>>(Q, K, Qp, KpT);
  qkt_scores<<<dim3(8, 8, BH), 256, 0, stream>>>(Q, K, Af);
  scan_evict<<<dim3(BH), 576, 0, stream>>>(Af, evt);
  attn_av<<<dim3(S_LEN / 8, BH), 256, 0, stream>>>(Af, Qp, KpT, evt, V, AO);
  split_a<<<dim3(4096), 256, 0, stream>>>(AO, ao_hi, ao_lo);
  split_T<<<dim3(32, 32, 1), 256, 0, stream>>>(wo, wo, wo, woT);
  gemm_mfma<1><<<dim3(16, 16, 1), 256, 0, stream>>>(ao_hi, ao_lo, woT, out);
}

// Round 11
// 988.493 us; speedup vs baseline: 1.0394x; 1.0394x over previous
//
#include <hip/hip_runtime.h>
#include <math.h>

// Problem constants (fixed by reference)
#define S_LEN    1024
#define NHEAD    16
#define DHEAD    128
#define HIDDEN   2048
#define BATCH    2
#define BH       32            // BATCH*NHEAD
#define CACHE_B  204           // heavy+recent budget
#define RECENT_B 102
#define QK_SCALE 0.08838834764831845f   // 1/sqrt(128)

typedef float v2f __attribute__((ext_vector_type(2)));
typedef float f32x4 __attribute__((ext_vector_type(4)));
typedef short short8v __attribute__((ext_vector_type(8)));

// ---------------------------------------------------------------------------
// bf16 hi/lo split helpers (RNE). a = hi + lo captures ~16-17 mantissa bits;
// a*b ~= ah*bh + al*bh + ah*bl (3 MFMAs) -> ~1e-5 abs error on these scales.
// ---------------------------------------------------------------------------
__device__ __forceinline__ unsigned short f2bf(float f) {
  unsigned u = __float_as_uint(f);
  u += 0x7fffu + ((u >> 16) & 1u);
  return (unsigned short)(u >> 16);
}
__device__ __forceinline__ float bf2f(unsigned short h) {
  return __uint_as_float(((unsigned)h) << 16);
}

// async global->LDS, 16B per lane. LDS dest must be wave-uniform base +
// lane*16 (HW ignores per-lane LDS scatter); global source IS per-lane.
__device__ __forceinline__ void gl16(const void* g, void* l) {
  __builtin_amdgcn_global_load_lds(
      (const __attribute__((address_space(1))) unsigned int*)g,
      (__attribute__((address_space(3))) unsigned int*)l, 16, 0, 0);
}

// MFMA via inline asm: avoids builtin signature (short8 vs bf16x8) ambiguity.
// gfx950 unified VGPR/AGPR file -> C/D in plain VGPRs is valid.
__device__ __forceinline__ void mfma_b(f32x4& d, short8v a, short8v b) {
  asm("v_mfma_f32_16x16x32_bf16 %0, %1, %2, %0" : "+v"(d) : "v"(a), "v"(b));
}

// ---------------------------------------------------------------------------
// split_a: X[f32] -> hi,lo bf16 (same layout). 4 elems/thread. (hs only now;
// the AO split is fused into attn_av's epilogue.)
// ---------------------------------------------------------------------------
__global__ __launch_bounds__(256) void split_a(
    const float* __restrict__ X, unsigned short* __restrict__ hi,
    unsigned short* __restrict__ lo) {
  const size_t i = ((size_t)blockIdx.x * 256 + threadIdx.x) * 4;
  const float4 v = *(const float4*)&X[i];
  const float f[4] = {v.x, v.y, v.z, v.w};
  unsigned short h[4], l[4];
#pragma unroll
  for (int j = 0; j < 4; ++j) {
    h[j] = f2bf(f[j]);
    l[j] = f2bf(f[j] - bf2f(h[j]));
  }
  *(ushort4*)&hi[i] = make_ushort4(h[0], h[1], h[2], h[3]);
  *(ushort4*)&lo[i] = make_ushort4(l[0], l[1], l[2], l[3]);
}

// ---------------------------------------------------------------------------
// split_T: W[k][n] f32 -> hiT,loT[n][k] bf16 (transpose+split), 64x64 tiles
// via padded LDS. z selects among up to 3 weights; out block stride 8M shorts.
// ---------------------------------------------------------------------------
__global__ __launch_bounds__(256) void split_T(
    const float* __restrict__ W0, const float* __restrict__ W1,
    const float* __restrict__ W2, unsigned short* __restrict__ outB) {
  __shared__ float Ts[64][65];
  const float* W = (blockIdx.z == 0) ? W0 : ((blockIdx.z == 1) ? W1 : W2);
  unsigned short* hiT = outB + (size_t)blockIdx.z * 8388608u;
  unsigned short* loT = hiT + 4194304u;
  const int k0 = blockIdx.y * 64, n0 = blockIdx.x * 64;
  const int r = threadIdx.x >> 4, c4 = (threadIdx.x & 15) * 4;
#pragma unroll
  for (int it = 0; it < 4; ++it) {
    const float4 v =
        *(const float4*)&W[(size_t)(k0 + it * 16 + r) * HIDDEN + n0 + c4];
    Ts[it * 16 + r][c4 + 0] = v.x;
    Ts[it * 16 + r][c4 + 1] = v.y;
    Ts[it * 16 + r][c4 + 2] = v.z;
    Ts[it * 16 + r][c4 + 3] = v.w;
  }
  __syncthreads();
#pragma unroll
  for (int it = 0; it < 4; ++it) {
    const int n = it * 16 + r;
    unsigned short h[4], l[4];
#pragma unroll
    for (int j = 0; j < 4; ++j) {
      const float f = Ts[c4 + j][n];
      h[j] = f2bf(f);
      l[j] = f2bf(f - bf2f(h[j]));
    }
    const size_t o = (size_t)(n0 + n) * HIDDEN + k0 + c4;
    *(ushort4*)&hiT[o] = make_ushort4(h[0], h[1], h[2], h[3]);
    *(ushort4*)&loT[o] = make_ushort4(l[0], l[1], l[2], l[3]);
  }
}

// ---------------------------------------------------------------------------
// bf16x3 MFMA GEMM, m97 structure: 128x128 tile, BK=32, 256 threads = 4
// waves in 2x2, each wave a 64x64 quadrant as 4x4 fragments of
// v_mfma_f32_16x16x32_bf16. A: [M][K] hi/lo; B: [N][K] (pre-transposed
// weight splits). MODE 0: C scatters to [B,H,S,D] per blockIdx.z.
// MODE 1: row-major C.
// ---------------------------------------------------------------------------
template <int MODE>
__global__ __launch_bounds__(256) void gemm_mfma(
    const unsigned short* __restrict__ Ahi,
    const unsigned short* __restrict__ Alo,
    const unsigned short* __restrict__ WT, float* __restrict__ C0) {
  __shared__ unsigned short AhS[128][32];
  __shared__ unsigned short AlS[128][32];
  __shared__ unsigned short BhS[128][32];
  __shared__ unsigned short BlS[128][32];
  const int tid = threadIdx.x;
  const int lane = tid & 63;
  const int wv = tid >> 6;
  const int wr = wv >> 1, wc = wv & 1;
  const int m0 = blockIdx.y * 128, n0 = blockIdx.x * 128;
  const unsigned short* BhiT =
      WT + (MODE == 0 ? (size_t)blockIdx.z * 8388608u : (size_t)0);
  const unsigned short* BloT = BhiT + 4194304u;

  f32x4 acc[4][4];
#pragma unroll
  for (int i = 0; i < 4; ++i)
#pragma unroll
    for (int j = 0; j < 4; ++j) acc[i][j] = (f32x4)(0.0f);

  const int r_st = tid >> 2;        // staging row base (0..63); +64 on l=1
  const int kc_st = (tid & 3) * 8;  // staging k element offset

  for (int k0 = 0; k0 < HIDDEN; k0 += 32) {
#pragma unroll
    for (int l = 0; l < 2; ++l) {
      const int r = r_st + l * 64;
      const size_t ga = (size_t)(m0 + r) * HIDDEN + (k0 + kc_st);
      const size_t gb = (size_t)(n0 + r) * HIDDEN + (k0 + kc_st);
      gl16(Ahi + ga, &AhS[r][kc_st]);
      gl16(Alo + ga, &AlS[r][kc_st]);
      gl16(BhiT + gb, &BhS[r][kc_st]);
      gl16(BloT + gb, &BlS[r][kc_st]);
    }
    __syncthreads();  // compiler drains vmcnt before barrier
    const int mrow = lane & 15;
    const int kb = (lane >> 4) * 8;
    short8v ah[4], al[4], bh[4], bl[4];
#pragma unroll
    for (int i = 0; i < 4; ++i) {
      ah[i] = *(const short8v*)&AhS[wr * 64 + i * 16 + mrow][kb];
      al[i] = *(const short8v*)&AlS[wr * 64 + i * 16 + mrow][kb];
      bh[i] = *(const short8v*)&BhS[wc * 64 + i * 16 + mrow][kb];
      bl[i] = *(const short8v*)&BlS[wc * 64 + i * 16 + mrow][kb];
    }
#pragma unroll
    for (int i = 0; i < 4; ++i)
#pragma unroll
      for (int j = 0; j < 4; ++j) {
        mfma_b(acc[i][j], ah[i], bh[j]);
        mfma_b(acc[i][j], al[i], bh[j]);
        mfma_b(acc[i][j], ah[i], bl[j]);
      }
    __syncthreads();
  }

  // C/D layout (m89/m91-verified): col = lane&15, row = (lane>>4)*4 + reg
  float* C = C0;
  if (MODE == 0) C += (size_t)blockIdx.z * ((size_t)BH * S_LEN * DHEAD);
#pragma unroll
  for (int i = 0; i < 4; ++i) {
    const int mbase = m0 + wr * 64 + i * 16 + ((lane >> 4) * 4);
#pragma unroll
    for (int j = 0; j < 4; ++j) {
      const int n = n0 + wc * 64 + j * 16 + (lane & 15);
#pragma unroll
      for (int rg = 0; rg < 4; ++rg) {
        const int m = mbase + rg;
        const float val = acc[i][j][rg];
        if (MODE == 0) {
          const int b = m >> 10, s = m & (S_LEN - 1);
          const int h = n >> 7, d = n & (DHEAD - 1);
          C[(((size_t)(b * NHEAD + h) * S_LEN + s) * DHEAD) + d] = val;
        } else {
          C[(size_t)m * HIDDEN + n] = val;
        }
      }
    }
  }
}

// ---------------------------------------------------------------------------
// RoPE in place on Q,K ([BH,S,D] layout).
// ---------------------------------------------------------------------------
__global__ __launch_bounds__(256) void rope_qk(float* __restrict__ Q,
                                               float* __restrict__ K) {
  int g = blockIdx.x * 4 + (threadIdx.x >> 6);  // row id over BH*S
  int lane = threadIdx.x & 63;
  int s = g & (S_LEN - 1);
  double invf = exp(-((double)(2 * lane) / 128.0) * log(10000.0));
  float angle = (float)s * (float)invf;
  float c = (float)cos((double)angle);
  float sn = (float)sin((double)angle);
  size_t base = (size_t)g * DHEAD;
  float q0 = Q[base + lane], q1 = Q[base + lane + 64];
  Q[base + lane] = q0 * c - q1 * sn;
  Q[base + lane + 64] = q1 * c + q0 * sn;
  float k0 = K[base + lane], k1 = K[base + lane + 64];
  K[base + lane] = k0 * c - k1 * sn;
  K[base + lane + 64] = k1 * c + k0 * sn;
}

// ---------------------------------------------------------------------------
// Per (b,h): mean |k| over first 204 roped tokens, stable argsort rank,
// keep top-6 dims; pack Qp[bh][s][0..5] (stride 8) and TRANSPOSED
// KpT[bh][j][s] (j=0..5, stride S_LEN) for attn_av's branchless phase 1.
// ---------------------------------------------------------------------------
__global__ __launch_bounds__(128) void keep_pack(
    const float* __restrict__ Q, const float* __restrict__ K,
    float* __restrict__ Qp, float* __restrict__ KpT) {
  int bh = blockIdx.x;
  int d = threadIdx.x;
  __shared__ float ma[128];
  __shared__ int kf[128];
  __shared__ int kidx[8];
  const float* Kb = K + (size_t)bh * S_LEN * DHEAD;
  const float* Qb = Q + (size_t)bh * S_LEN * DHEAD;
  float sum = 0.0f;
  for (int s = 0; s < CACHE_B; ++s) sum += fabsf(Kb[(size_t)s * DHEAD + d]);
  ma[d] = sum / 204.0f;
  __syncthreads();
  float v = ma[d];
  int rank = 0;
  for (int e = 0; e < 128; ++e) {
    float u = ma[e];
    rank += (u < v) || (u == v && e < d);  // stable-argsort rank
  }
  int keep = (rank >= 128 - 6);
  kf[d] = keep;
  __syncthreads();
  if (keep) {
    int pos = 0;
    for (int e = 0; e < d; ++e) pos += kf[e];
    kidx[pos] = d;
  }
  __syncthreads();
  int i0 = kidx[0], i1 = kidx[1], i2 = kidx[2];
  int i3 = kidx[3], i4 = kidx[4], i5 = kidx[5];
  float* Kt = KpT + (size_t)bh * 6 * S_LEN;
  for (int s = threadIdx.x; s < S_LEN; s += 128) {
    size_t src = (size_t)s * DHEAD;
    size_t dst = ((size_t)bh * S_LEN + s) * 8;
    Qp[dst + 0] = Qb[src + i0]; Qp[dst + 1] = Qb[src + i1];
    Qp[dst + 2] = Qb[src + i2]; Qp[dst + 3] = Qb[src + i3];
    Qp[dst + 4] = Qb[src + i4]; Qp[dst + 5] = Qb[src + i5];
    Kt[0 * S_LEN + s] = Kb[src + i0];
    Kt[1 * S_LEN + s] = Kb[src + i1];
    Kt[2 * S_LEN + s] = Kb[src + i2];
    Kt[3 * S_LEN + s] = Kb[src + i3];
    Kt[4 * S_LEN + s] = Kb[src + i4];
    Kt[5 * S_LEN + s] = Kb[src + i5];
  }
}

// ---------------------------------------------------------------------------
// Batched A_full[bh][t][s] = QK_SCALE * Q[t]·K[s], lower-triangular tiles
// only. fp32 (exactness matters for the eviction argmin path).
// ---------------------------------------------------------------------------
__global__ __launch_bounds__(256) void qkt_scores(
    const float* __restrict__ Q, const float* __restrict__ K,
    float* __restrict__ Af) {
  if (blockIdx.x > blockIdx.y) return;  // strictly-upper tiles never read
  __shared__ float Qs[16][132];
  __shared__ float Ks[16][132];
  const int bh = blockIdx.z;
  const int tid = threadIdx.x;
  const int tx = tid & 15, ty = tid >> 4;
  const int m0 = blockIdx.y * 128, n0 = blockIdx.x * 128;
  const float* Qb = Q + (size_t)bh * S_LEN * DHEAD;
  const float* Kb = K + (size_t)bh * S_LEN * DHEAD;
  v2f acc[8][4];
#pragma unroll
  for (int i = 0; i < 8; ++i)
#pragma unroll
    for (int p = 0; p < 4; ++p) acc[i][p] = (v2f)(0.0f);

  for (int k0 = 0; k0 < DHEAD; k0 += 16) {
#pragma unroll
    for (int l = 0; l < 2; ++l) {
      int f = tid + l * 256;
      int r = f >> 2, c = (f & 3) * 4;
      const float4 q = *(const float4*)&Qb[(size_t)(m0 + r) * DHEAD + k0 + c];
      Qs[c + 0][r] = q.x; Qs[c + 1][r] = q.y;
      Qs[c + 2][r] = q.z; Qs[c + 3][r] = q.w;
      const float4 kv = *(const float4*)&Kb[(size_t)(n0 + r) * DHEAD + k0 + c];
      Ks[c + 0][r] = kv.x; Ks[c + 1][r] = kv.y;
      Ks[c + 2][r] = kv.z; Ks[c + 3][r] = kv.w;
    }
    __syncthreads();
#pragma unroll
    for (int kk = 0; kk < 16; ++kk) {
      float av[8];
      v2f bv[4];
      *(float4*)&av[0] = *(float4*)&Qs[kk][ty * 4];
      *(float4*)&av[4] = *(float4*)&Qs[kk][64 + ty * 4];
      const float4 b0 = *(const float4*)&Ks[kk][tx * 4];
      const float4 b1 = *(const float4*)&Ks[kk][64 + tx * 4];
      bv[0] = (v2f){b0.x, b0.y};
      bv[1] = (v2f){b0.z, b0.w};
      bv[2] = (v2f){b1.x, b1.y};
      bv[3] = (v2f){b1.z, b1.w};
#pragma unroll
      for (int i = 0; i < 8; ++i) {
        const v2f a2 = (v2f){av[i], av[i]};
#pragma unroll
        for (int p = 0; p < 4; ++p) acc[i][p] = a2 * bv[p] + acc[i][p];
      }
    }
    __syncthreads();
  }
  float* Cb = Af + (size_t)bh * S_LEN * S_LEN;
#pragma unroll
  for (int gi = 0; gi < 2; ++gi)
#pragma unroll
    for (int i = 0; i < 4; ++i) {
      const int t = m0 + gi * 64 + ty * 4 + i;
      const int ia = gi * 4 + i;
#pragma unroll
      for (int gj = 0; gj < 2; ++gj) {
        const int s = n0 + gj * 64 + tx * 4;
        float4 o;
        o.x = acc[ia][gj * 2 + 0].x * QK_SCALE;
        o.y = acc[ia][gj * 2 + 0].y * QK_SCALE;
        o.z = acc[ia][gj * 2 + 1].x * QK_SCALE;
        o.w = acc[ia][gj * 2 + 1].y * QK_SCALE;
        *(float4*)&Cb[(size_t)t * S_LEN + s] = o;
      }
    }
}

// ---------------------------------------------------------------------------
// Sequential H2O eviction scan v8 (best verified: 367 us, rounds 6/7).
// Round-10 finding: v11 (8 producers + consumer, loads fully OFF the
// consumer path) ran at the SAME ~1150 cy/step -> the per-step serial
// chain (tournament + DPP wave-min + readlane/ballot + hazards) is itself
// ~1000+ cy; staging scheme is irrelevant. Reverting to the simplest,
// fastest verified form: loads in-consumer, evictions to LDS (pure-load
// VMEM stream -> precise counted vmcnt), 6-deep rotation, slot tournament.
// ---------------------------------------------------------------------------
template <int CTRL, int RMASK>
__device__ __forceinline__ float dpp_fmin(float x) {
  const int xi = __builtin_bit_cast(int, x);
  const int y = __builtin_amdgcn_update_dpp(xi, xi, CTRL, RMASK, 0xF, false);
  return fminf(x, __builtin_bit_cast(float, y));
}
__device__ __forceinline__ float wave_min_f32(float x) {
  x = dpp_fmin<0x111, 0xF>(x);  // row_shr:1
  x = dpp_fmin<0x112, 0xF>(x);  // row_shr:2
  x = dpp_fmin<0x114, 0xF>(x);  // row_shr:4
  x = dpp_fmin<0x118, 0xF>(x);  // row_shr:8
  x = dpp_fmin<0x142, 0xA>(x);  // row_bcast:15
  x = dpp_fmin<0x143, 0xC>(x);  // row_bcast:31
  return __builtin_bit_cast(
      float, __builtin_amdgcn_readlane(__builtin_bit_cast(int, x), 63));
}

__global__ __launch_bounds__(64, 1) void scan_evict(
    const float* __restrict__ Af, int* __restrict__ evt) {
  __shared__ int evt_lds[S_LEN];  // 4 KiB
  const int bh = blockIdx.x;
  const int lane = threadIdx.x;
  const float* Ab = Af + (size_t)bh * S_LEN * S_LEN;
  int* evtb = evt + bh * S_LEN;

  {  // evt init in LDS: INT_MAX everywhere
    const int4 big = make_int4(0x7fffffff, 0x7fffffff, 0x7fffffff, 0x7fffffff);
#pragma unroll
    for (int j = 0; j < 4; ++j) *(int4*)&evt_lds[j * 256 + lane * 4] = big;
  }

  unsigned evmask = 0;
  unsigned elig = (lane < 6) ? 0xFFFFu : (lane == 6 ? 0x7Fu : 0u);  // s <= 102

  const float* lb = Ab + lane * 16;  // lane l owns s = 16l..16l+15
  float4 A0[4], A1[4], A2[4], A3[4], A4[4], A5[4];

#define SB() __builtin_amdgcn_sched_barrier(0)

#define LDROW(R, r)                                      \
  do {                                                   \
    int r_ = (r);                                        \
    r_ = r_ > 1022 ? 1022 : r_;                          \
    const float* rb = lb + (size_t)r_ * S_LEN;           \
    R[0] = *(const float4*)(rb + 0);                     \
    R[1] = *(const float4*)(rb + 4);                     \
    R[2] = *(const float4*)(rb + 8);                     \
    R[3] = *(const float4*)(rb + 12);                    \
  } while (0)

#define STEP(R, T)                                                          \
  do {                                                                      \
    const int t_ = (T);                                                     \
    const int snew = t_ - 103; /* newly eligible s (idempotent @205) */     \
    elig |= ((snew >> 4) == lane) ? (1u << (snew & 15)) : 0u;               \
    const unsigned ue = elig & ~evmask;                                     \
    float fv[16];                                                           \
    _Pragma("unroll") for (int p = 0; p < 4; ++p) {                         \
      fv[p * 4 + 0] = ((ue >> (p * 4 + 0)) & 1u) ? R[p].x : INFINITY;       \
      fv[p * 4 + 1] = ((ue >> (p * 4 + 1)) & 1u) ? R[p].y : INFINITY;       \
      fv[p * 4 + 2] = ((ue >> (p * 4 + 2)) & 1u) ? R[p].z : INFINITY;       \
      fv[p * 4 + 3] = ((ue >> (p * 4 + 3)) & 1u) ? R[p].w : INFINITY;       \
    }                                                                       \
    /* (min, first-slot) tournament; <= prefers left = lower slot */        \
    float m8[8]; int s8[8];                                                 \
    _Pragma("unroll") for (int i = 0; i < 8; ++i) {                         \
      m8[i] = fminf(fv[2 * i], fv[2 * i + 1]);                              \
      s8[i] = (fv[2 * i] <= fv[2 * i + 1]) ? (2 * i) : (2 * i + 1);         \
    }                                                                       \
    float m4[4]; int s4[4];                                                 \
    _Pragma("unroll") for (int i = 0; i < 4; ++i) {                         \
      m4[i] = fminf(m8[2 * i], m8[2 * i + 1]);                              \
      s4[i] = (m8[2 * i] <= m8[2 * i + 1]) ? s8[2 * i] : s8[2 * i + 1];     \
    }                                                                       \
    float m2[2]; int s2[2];                                                 \
    m2[0] = fminf(m4[0], m4[1]); s2[0] = (m4[0] <= m4[1]) ? s4[0] : s4[1];  \
    m2[1] = fminf(m4[2], m4[3]); s2[1] = (m4[2] <= m4[3]) ? s4[2] : s4[3];  \
    const float vmin = fminf(m2[0], m2[1]);                                 \
    const int bloc = (m2[0] <= m2[1]) ? s2[0] : s2[1];                      \
    const float best = wave_min_f32(vmin);                                  \
    const unsigned long long msk = __ballot(vmin == best);                  \
    const int winner = __ffsll(msk) - 1; /* lowest lane = lowest s */       \
    if (lane == winner) {                                                   \
      evmask |= 1u << bloc;                                                 \
      evt_lds[lane * 16 + bloc] = t_;  /* ds_write: lgkmcnt, not vmcnt */   \
    }                                                                       \
  } while (0)

  // prologue: A0..A5 <- rows 204..209 (pure global loads)
  LDROW(A0, 204); LDROW(A1, 205); LDROW(A2, 206);
  LDROW(A3, 207); LDROW(A4, 208); LDROW(A5, 209);
  SB();

  // 136 groups x 6 steps: t = 205..1020; refill each buffer 6 rows ahead.
  for (int g = 0; g < 136; ++g) {
    const int t0 = 205 + g * 6;
    STEP(A0, t0 + 0); LDROW(A0, t0 + 5); SB();
    STEP(A1, t0 + 1); LDROW(A1, t0 + 6); SB();
    STEP(A2, t0 + 2); LDROW(A2, t0 + 7); SB();
    STEP(A3, t0 + 3); LDROW(A3, t0 + 8); SB();
    STEP(A4, t0 + 4); LDROW(A4, t0 + 9); SB();
    STEP(A5, t0 + 5); LDROW(A5, t0 + 10); SB();
  }
  // tail: t = 1021..1023 consume rows 1020..1022 (in A0..A2)
  STEP(A0, 1021);
  STEP(A1, 1022);
  STEP(A2, 1023);

  // flush evt LDS -> global (all ds_writes drained first)
  asm volatile("s_waitcnt lgkmcnt(0)" ::: "memory");
  SB();
#pragma unroll
  for (int j = 0; j < 4; ++j)
    *(int4*)&evtb[j * 256 + lane * 4] =
        *(const int4*)&evt_lds[j * 256 + lane * 4];
#undef LDROW
#undef STEP
#undef SB
}

// ---------------------------------------------------------------------------
// Final attention v3 — phase 1 branchless (KpT + cndmask); phase 2
// s-partitioned (1x V traffic), cross-wave reduce overlaid on P.
// Round-10 change: epilogue writes the bf16 hi/lo split of the output
// DIRECTLY (ao_hi | ao_lo halves of the old AO slot) -> the separate
// split_a(AO) pass (16MB read + launch) is eliminated. Same RNE split,
// numerically identical to split-after.
// ---------------------------------------------------------------------------
__global__ __launch_bounds__(256) void attn_av(
    const float* __restrict__ Af, const float* __restrict__ Qp,
    const float* __restrict__ KpT, const int* __restrict__ evt,
    const float* __restrict__ V, unsigned short* __restrict__ ao_hi,
    unsigned short* __restrict__ ao_lo) {
  const int t0 = blockIdx.x * 8;
  const int bh = blockIdx.y;
  __shared__ float P[8][S_LEN];  // 32 KB; first 16 KB reused as reduce buf
  __shared__ float rinv[8];
  const int tid = threadIdx.x;
  const int lane = tid & 63, wave = tid >> 6;
  const float* Ab = Af + (size_t)bh * S_LEN * S_LEN;
  const int* eb = evt + bh * S_LEN;
  const float* Kt = KpT + (size_t)bh * 6 * S_LEN;

  // ---- phase 1: merged scores + softmax -> P, rinv ----
  for (int rr = 0; rr < 2; ++rr) {
    const int r = wave * 2 + rr;
    const int t = t0 + r;
    float qp[6];
#pragma unroll
    for (int j = 0; j < 6; ++j) qp[j] = Qp[((size_t)bh * S_LEN + t) * 8 + j];
    float vals[16];
    float m = -INFINITY;
#pragma unroll
    for (int i = 0; i < 16; ++i) {
      const int s = lane + i * 64;
      const float full = Ab[(size_t)t * S_LEN + s];
      float low = qp[0] * Kt[s];
      low += qp[1] * Kt[S_LEN + s];
      low += qp[2] * Kt[2 * S_LEN + s];
      low += qp[3] * Kt[3 * S_LEN + s];
      low += qp[4] * Kt[4 * S_LEN + s];
      low += qp[5] * Kt[5 * S_LEN + s];
      const int ev = eb[s];
      const float sc = (ev <= t) ? (QK_SCALE * low) : full;
      vals[i] = sc;
      m = fmaxf(m, (s <= t) ? sc : -INFINITY);
    }
    for (int off = 32; off; off >>= 1) m = fmaxf(m, __shfl_xor(m, off, 64));
    float sum = 0.0f;
#pragma unroll
    for (int i = 0; i < 16; ++i) {
      const int s = lane + i * 64;
      const float e = expf(vals[i] - m);
      const float p = (s <= t) ? e : 0.0f;  // select after exp: NaN-safe
      sum += p;
      P[r][s] = p;
    }
    for (int off = 32; off; off >>= 1) sum += __shfl_xor(sum, off, 64);
    if (lane == 0) rinv[r] = 1.0f / sum;
  }
  __syncthreads();

  // ---- phase 2: out = P·V, s-partitioned across waves (1x V traffic) ----
  const int NC = (t0 + 8) >> 2;  // number of 4-row s-chunks
  const float* Vb = V + (size_t)bh * S_LEN * DHEAD;
  const int d2 = lane * 2;
  float accx[8], accy[8];
#pragma unroll
  for (int r = 0; r < 8; ++r) { accx[r] = 0.0f; accy[r] = 0.0f; }
  for (int c = wave; c < NC; c += 4) {
    const int s0 = c * 4;
    float4 p4[8];
#pragma unroll
    for (int r = 0; r < 8; ++r) p4[r] = *(const float4*)&P[r][s0];
    const float2 v0 = *(const float2*)&Vb[(size_t)(s0 + 0) * DHEAD + d2];
    const float2 v1 = *(const float2*)&Vb[(size_t)(s0 + 1) * DHEAD + d2];
    const float2 v2 = *(const float2*)&Vb[(size_t)(s0 + 2) * DHEAD + d2];
    const float2 v3 = *(const float2*)&Vb[(size_t)(s0 + 3) * DHEAD + d2];
#pragma unroll
    for (int r = 0; r < 8; ++r) {
      accx[r] += p4[r].x * v0.x + p4[r].y * v1.x + p4[r].z * v2.x +
                 p4[r].w * v3.x;
      accy[r] += p4[r].x * v0.y + p4[r].y * v1.y + p4[r].z * v2.y +
                 p4[r].w * v3.y;
    }
  }
  __syncthreads();  // all waves done reading P -> safe to overlay
  float* red = &P[0][0];  // red[w][r][128]: 4*8*128 floats = 16 KB
#pragma unroll
  for (int r = 0; r < 8; ++r) {
    float2 pr; pr.x = accx[r]; pr.y = accy[r];
    *(float2*)&red[((wave * 8 + r) << 7) + d2] = pr;
  }
  __syncthreads();
  // final: 1024 outputs; tid -> r = tid>>5, d4 = (tid&31)*4
  const int r = tid >> 5;
  const int d4 = (tid & 31) * 4;
  const int t = t0 + r;
  float4 o = make_float4(0.f, 0.f, 0.f, 0.f);
#pragma unroll
  for (int w = 0; w < 4; ++w) {
    const float4 part = *(const float4*)&red[((w * 8 + r) << 7) + d4];
    o.x += part.x; o.y += part.y; o.z += part.z; o.w += part.w;
  }
  const float ri = rinv[r];
  o.x *= ri; o.y *= ri; o.z *= ri; o.w *= ri;
  // fused bf16 hi/lo split of the attention output (replaces split_a(AO))
  const float oc[4] = {o.x, o.y, o.z, o.w};
  unsigned short h4[4], l4[4];
#pragma unroll
  for (int j = 0; j < 4; ++j) {
    h4[j] = f2bf(oc[j]);
    l4[j] = f2bf(oc[j] - bf2f(h4[j]));
  }
  const int b = bh >> 4, h = bh & 15;
  const size_t idx = ((size_t)(b * S_LEN + t)) * HIDDEN + h * DHEAD + d4;
  *(ushort4*)&ao_hi[idx] = make_ushort4(h4[0], h4[1], h4[2], h4[3]);
  *(ushort4*)&ao_lo[idx] = make_ushort4(l4[0], l4[1], l4[2], l4[3]);
}

// ---------------------------------------------------------------------------
// Workspace plan: Q,K,V (48MB) | Af (128MB) | Qp | KpT | evt | AO-slot.
// bf16 split buffers for hs/w live INSIDE Af (dead until qkt_scores writes
// it); the AO slot is reinterpreted as [ao_hi 8MB | ao_lo 8MB] (written by
// attn_av's fused epilogue). woT still lands in Af after attn_av's last read.
// ---------------------------------------------------------------------------
extern "C" void kernel_launch(void* const* d_in, const int* in_sizes, int n_in,
                              void* d_out, int out_size, void* d_ws,
                              size_t ws_size, hipStream_t stream) {
  const float* hs = (const float*)d_in[0];
  const float* wq = (const float*)d_in[1];
  const float* wk = (const float*)d_in[2];
  const float* wv = (const float*)d_in[3];
  const float* wo = (const float*)d_in[4];
  float* out = (float*)d_out;

  const size_t SZ_QKV = (size_t)BH * S_LEN * DHEAD;
  float* Q = (float*)d_ws;
  float* K = Q + SZ_QKV;
  float* V = K + SZ_QKV;
  float* Af = V + SZ_QKV;
  float* Qp = Af + (size_t)BH * S_LEN * S_LEN;
  float* KpT = Qp + (size_t)BH * S_LEN * 8;  // 6*S_LEN*BH floats < old Kp slot
  int* evt = (int*)(KpT + (size_t)BH * S_LEN * 8);
  float* AOslot = (float*)(evt + BH * S_LEN);
  unsigned short* ao_hi = (unsigned short*)AOslot;      // 8 MiB
  unsigned short* ao_lo = ao_hi + 4194304u;             // 8 MiB

  // split-buffer aliases inside Af (ushort units; block = 2048*2048 = 4194304)
  unsigned short* U = (unsigned short*)Af;
  unsigned short* wT = U;                        // 3 x (hi+lo) = 48 MiB
  unsigned short* hs_hi = U + 25165824u;         // 3*8388608
  unsigned short* hs_lo = hs_hi + 4194304u;
  unsigned short* woT = U + 8388608u;            // hi at +8M, lo at +12M

  split_T<<<dim3(32, 32, 3), 256, 0, stream>>>(wq, wk, wv, wT);
  split_a<<<dim3(4096), 256, 0, stream>>>(hs, hs_hi, hs_lo);
  gemm_mfma<0><<<dim3(16, 16, 3), 256, 0, stream>>>(hs_hi, hs_lo, wT, Q);
  rope_qk<<<dim3(BH * S_LEN / 4), 256, 0, stream>>>(Q, K);
  keep_pack<<<dim3(BH), 128, 0, stream>>>(Q, K, Qp, KpT);
  qkt_scores<<<dim3(8, 8, BH), 256, 0, stream>>>(Q, K, Af);
  scan_evict<<<dim3(BH), 64, 0, stream>>>(Af, evt);
  attn_av<<<dim3(S_LEN / 8, BH), 256, 0, stream>>>(Af, Qp, KpT, evt, V,
                                                   ao_hi, ao_lo);
  split_T<<<dim3(32, 32, 1), 256, 0, stream>>>(wo, wo, wo, woT);
  gemm_mfma<1><<<dim3(16, 16, 1), 256, 0, stream>>>(ao_hi, ao_lo, woT, out);
}